// Round 3
// baseline (1721.289 us; speedup 1.0000x reference)
//
#include <hip/hip_runtime.h>

#define NV 50000
#define NE 5000
#define NE8 5120        // padded u8 row stride (keeps uint loads aligned)
#define NC 16
#define TAU_INV 2.0f
#define EPS 1e-8f

#define NCH 100         // v-chunks (part round-trip 67.6 MB)
#define VCH 500         // NV / NCH ; LDS slice = 500*32*4 = 62.5 KB
#define GRP 5           // rows per prefetch batch; 2*GRP must divide VCH (10 | 500)
#define NXB 5           // x-blocks; 5 * 256 lanes * 4 edges = 5120 slots >= 5000
#define NBLK (NXB * NCH)   // 500
#define NLANE 5120

typedef float vf4 __attribute__((ext_vector_type(4)));

// ---------------- softmax: one thread per row, both pred_s and pred_t.
// Output layout: p[v][32] = [softmax(pred_s[v]) (16) | softmax(pred_t[v]) (16)]
__global__ __launch_bounds__(256) void softmax_kernel(
    const float* __restrict__ pred_s, const float* __restrict__ pred_t,
    float* __restrict__ p) {
  int i = blockIdx.x * 256 + threadIdx.x;
  if (i >= 2 * NV) return;
  const float* src;
  float* dst;
  if (i < NV) { src = pred_s + (size_t)i * NC; dst = p + (size_t)i * 32; }
  else        { int j = i - NV; src = pred_t + (size_t)j * NC; dst = p + (size_t)j * 32 + 16; }
  float4 a = ((const float4*)src)[0];
  float4 b = ((const float4*)src)[1];
  float4 c = ((const float4*)src)[2];
  float4 d = ((const float4*)src)[3];
  float x[16] = {a.x,a.y,a.z,a.w, b.x,b.y,b.z,b.w, c.x,c.y,c.z,c.w, d.x,d.y,d.z,d.w};
  float mx = x[0];
#pragma unroll
  for (int k = 1; k < 16; ++k) mx = fmaxf(mx, x[k]);
  float sum = 0.f;
#pragma unroll
  for (int k = 0; k < 16; ++k) { x[k] = expf(x[k] - mx); sum += x[k]; }
  float inv = 1.f / sum;
#pragma unroll
  for (int k = 0; k < 16; ++k) x[k] *= inv;
  float4 o0 = {x[0], x[1], x[2], x[3]};
  float4 o1 = {x[4], x[5], x[6], x[7]};
  float4 o2 = {x[8], x[9], x[10], x[11]};
  float4 o3 = {x[12], x[13], x[14], x[15]};
  ((float4*)dst)[0] = o0;
  ((float4*)dst)[1] = o1;
  ((float4*)dst)[2] = o2;
  ((float4*)dst)[3] = o3;
}

// ---------------- compress: H f32 (1 GB) -> u8 0/1 (250 MB, padded rows).
// Pure linear stream, grid-stride over rows; NT loads keep H out of L3 so
// H8/p/part stay resident for the downstream kernels.
__global__ __launch_bounds__(256) void compress_kernel(
    const float* __restrict__ H, unsigned char* __restrict__ H8) {
  for (int row = blockIdx.x; row < NV; row += gridDim.x) {
    const float* src = H + (size_t)row * NE;        // 16B-aligned (5000 % 4 == 0)
    unsigned char* dst = H8 + (size_t)row * NE8;    // 8B-aligned  (5120 % 8 == 0)
    for (int u = threadIdx.x; u < 625; u += 256) {  // 625 * 8 floats = 5000
      vf4 a = __builtin_nontemporal_load((const vf4*)(src + (size_t)u * 8));
      vf4 b = __builtin_nontemporal_load((const vf4*)(src + (size_t)u * 8 + 4));
      uint x0 = (uint)(a.x != 0.f) | ((uint)(a.y != 0.f) << 8) |
                ((uint)(a.z != 0.f) << 16) | ((uint)(a.w != 0.f) << 24);
      uint x1 = (uint)(b.x != 0.f) | ((uint)(b.y != 0.f) << 8) |
                ((uint)(b.z != 0.f) << 16) | ((uint)(b.w != 0.f) << 24);
      uint2 w; w.x = x0; w.y = x1;
      *(uint2*)(dst + (size_t)u * 8) = w;           // normal store: want L3-resident
    }
  }
}

// per-row FMA body: decode 4 edge-flags from one uint, accumulate S/T/deg
#define ROW_BODY(ROW, HW) {                                                  \
    const float4* __restrict__ r = (const float4*)(lp + (size_t)(ROW) * 32); \
    float hx = (float)((HW) & 255u);                                         \
    float hy = (float)(((HW) >> 8) & 255u);                                  \
    float hz = (float)(((HW) >> 16) & 255u);                                 \
    float hw_ = (float)((HW) >> 24);                                         \
    dg.x += hx; dg.y += hy; dg.z += hz; dg.w += hw_;                         \
    {                                                                        \
      float4 s0 = r[0], s1 = r[1], s2 = r[2], s3 = r[3];                     \
      float sv[16] = {s0.x,s0.y,s0.z,s0.w, s1.x,s1.y,s1.z,s1.w,              \
                      s2.x,s2.y,s2.z,s2.w, s3.x,s3.y,s3.z,s3.w};             \
      _Pragma("unroll")                                                      \
      for (int k = 0; k < 16; ++k) {                                         \
        aS[k].x = fmaf(hx, sv[k], aS[k].x);                                  \
        aS[k].y = fmaf(hy, sv[k], aS[k].y);                                  \
        aS[k].z = fmaf(hz, sv[k], aS[k].z);                                  \
        aS[k].w = fmaf(hw_, sv[k], aS[k].w);                                 \
      }                                                                      \
    }                                                                        \
    {                                                                        \
      float4 t0 = r[4], t1 = r[5], t2 = r[6], t3 = r[7];                     \
      float tv[16] = {t0.x,t0.y,t0.z,t0.w, t1.x,t1.y,t1.z,t1.w,              \
                      t2.x,t2.y,t2.z,t2.w, t3.x,t3.y,t3.z,t3.w};             \
      _Pragma("unroll")                                                      \
      for (int k = 0; k < 16; ++k) {                                         \
        aT[k].x = fmaf(hx, tv[k], aT[k].x);                                  \
        aT[k].y = fmaf(hy, tv[k], aT[k].y);                                  \
        aT[k].z = fmaf(hz, tv[k], aT[k].z);                                  \
        aT[k].w = fmaf(hw_, tv[k], aT[k].w);                                 \
      }                                                                      \
    }                                                                        \
  }

// ---------------- main accumulation, 4 edges per lane, u8 H stream (4 B/lane/row),
// copy-free A/B register double-buffer, XCD-slab swizzle.
// part layout: part[y][k][NLANE], k: 0..15 S, 16..31 T, 32 deg
__global__ __launch_bounds__(256) void accum_kernel(
    const unsigned char* __restrict__ H8, const float* __restrict__ p,
    float* __restrict__ part) {
  __shared__ float lp[VCH * 32];   // 62.5 KB
  int b = blockIdx.x;
  // NBLK=500: blocks 0..495 swizzle bijectively (8 XCD slabs of 62), rest identity
  int item;
  if (b < 496) item = (b & 7) * 62 + (b >> 3);
  else         item = b;
  int xb = item % NXB;
  int y  = item / NXB;
  int e0 = 4 * (xb * 256 + (int)threadIdx.x);
  if (e0 > NE - 4) e0 = NE - 4;   // dup lanes write identical values: benign
  int v0 = y * VCH;

  // stage the p slice (contiguous 64 KB) into LDS, coalesced float4
  {
    const float4* __restrict__ src = (const float4*)(p + (size_t)v0 * 32);
    float4* dst = (float4*)lp;
    for (int i = threadIdx.x; i < VCH * 8; i += 256) dst[i] = src[i];
  }
  __syncthreads();

  float4 aS[16], aT[16], dg;
#pragma unroll
  for (int k = 0; k < 16; ++k) {
    aS[k] = make_float4(0.f, 0.f, 0.f, 0.f);
    aT[k] = make_float4(0.f, 0.f, 0.f, 0.f);
  }
  dg = make_float4(0.f, 0.f, 0.f, 0.f);

  const unsigned char* __restrict__ hp = H8 + (size_t)v0 * NE8 + e0;

  uint hA[GRP], hB[GRP];
#pragma unroll
  for (int u = 0; u < GRP; ++u)
    hA[u] = *(const uint*)(hp + (size_t)u * NE8);
#pragma unroll
  for (int u = 0; u < GRP; ++u)
    hB[u] = *(const uint*)(hp + (size_t)(GRP + u) * NE8);

  for (int vb = 0; vb < VCH; vb += 2 * GRP) {
    // compute batch A (rows vb .. vb+GRP-1), then refill A from vb+2*GRP
#pragma unroll
    for (int u = 0; u < GRP; ++u) ROW_BODY(vb + u, hA[u])
    {
      int nb = vb + 2 * GRP; if (nb > VCH - GRP) nb = VCH - GRP;  // tail: benign re-read
#pragma unroll
      for (int u = 0; u < GRP; ++u)
        hA[u] = *(const uint*)(hp + (size_t)(nb + u) * NE8);
    }
    // compute batch B (rows vb+GRP .. vb+2*GRP-1), then refill B from vb+3*GRP
#pragma unroll
    for (int u = 0; u < GRP; ++u) ROW_BODY(vb + GRP + u, hB[u])
    {
      int nb = vb + 3 * GRP; if (nb > VCH - GRP) nb = VCH - GRP;
#pragma unroll
      for (int u = 0; u < GRP; ++u)
        hB[u] = *(const uint*)(hp + (size_t)(nb + u) * NE8);
    }
  }

  // normal stores: part (67.6 MB) stays L3-resident for reduce_kernel
  float* op = part + (size_t)y * 33 * NLANE + e0;
#pragma unroll
  for (int k = 0; k < 16; ++k) {
    vf4 w = {aS[k].x, aS[k].y, aS[k].z, aS[k].w};
    *(vf4*)(op + (size_t)k * NLANE) = w;
  }
#pragma unroll
  for (int k = 0; k < 16; ++k) {
    vf4 w = {aT[k].x, aT[k].y, aT[k].z, aT[k].w};
    *(vf4*)(op + (size_t)(16 + k) * NLANE) = w;
  }
  {
    vf4 w = {dg.x, dg.y, dg.z, dg.w};
    *(vf4*)(op + (size_t)32 * NLANE) = w;
  }
}

// ---------------- reduce the NCH partials: acc[k][NLANE] = sum_y part[y][k][NLANE]
__global__ __launch_bounds__(256) void reduce_kernel(
    const float* __restrict__ part, float* __restrict__ acc) {
  int i = blockIdx.x * 256 + threadIdx.x;
  if (i >= 33 * NLANE) return;
  float s = 0.f;
#pragma unroll 4
  for (int y = 0; y < NCH; ++y)
    s += part[(size_t)y * 33 * NLANE + i];
  acc[i] = s;
}

// ---------------- per-edge KL + masked reduction (single block, 256 threads)
// acc layout: acc[k*NLANE + e]; S at k, T at 16+k, deg at 32
__global__ __launch_bounds__(256) void kl_kernel(
    const float* __restrict__ acc, const unsigned char* __restrict__ e_mask,
    float* __restrict__ out) {
  __shared__ float snum[4];
  __shared__ float scnt[4];
  int t = threadIdx.x;
  float num = 0.f, cnt = 0.f;
  for (int e = t; e < NE; e += 256) {
    if (e_mask[e]) {
      float deg = acc[(size_t)32 * NLANE + e];
      float invd = 1.f / deg;
      float kl = 0.f;
#pragma unroll
      for (int k = 0; k < 16; ++k) {
        float ms = acc[(size_t)k * NLANE + e] * invd;
        float mt = acc[(size_t)(16 + k) * NLANE + e] * invd;
        float xs = ms * TAU_INV + EPS;
        float xt = mt * TAU_INV + EPS;
        kl += xt * (logf(xt) - logf(xs));
      }
      num += kl;
      cnt += 1.f;
    }
  }
#pragma unroll
  for (int off = 32; off > 0; off >>= 1) {
    num += __shfl_down(num, off, 64);
    cnt += __shfl_down(cnt, off, 64);
  }
  if ((t & 63) == 0) { snum[t >> 6] = num; scnt[t >> 6] = cnt; }
  __syncthreads();
  if (t == 0) {
    float n = snum[0] + snum[1] + snum[2] + snum[3];
    float c2 = scnt[0] + scnt[1] + scnt[2] + scnt[3];
    out[0] = n / fmaxf(c2, 1.f);
  }
}

extern "C" void kernel_launch(void* const* d_in, const int* in_sizes, int n_in,
                              void* d_out, int out_size, void* d_ws, size_t ws_size,
                              hipStream_t stream) {
  const float* pred_s = (const float*)d_in[0];
  const float* pred_t = (const float*)d_in[1];
  const float* H      = (const float*)d_in[2];
  const unsigned char* e_mask = (const unsigned char*)d_in[3];

  float* ws   = (float*)d_ws;
  float* p    = ws;                                    // NV*32         (6.40 MB)
  float* acc  = ws + (size_t)NV * 32;                  // 33*NLANE      (0.68 MB)
  float* part = acc + (size_t)33 * NLANE;              // NCH*33*NLANE  (67.6 MB)
  unsigned char* H8 = (unsigned char*)(part + (size_t)NCH * 33 * NLANE);  // NV*NE8 (256 MB)

  softmax_kernel<<<dim3((2 * NV + 255) / 256), 256, 0, stream>>>(pred_s, pred_t, p);
  compress_kernel<<<dim3(2048), 256, 0, stream>>>(H, H8);
  accum_kernel<<<dim3(NBLK), 256, 0, stream>>>(H8, p, part);
  reduce_kernel<<<dim3((33 * NLANE + 255) / 256), 256, 0, stream>>>(part, acc);
  kl_kernel<<<1, 256, 0, stream>>>(acc, e_mask, (float*)d_out);
}

// Round 4
// 1431.555 us; speedup vs baseline: 1.2024x; 1.2024x over previous
//
#include <hip/hip_runtime.h>

#define NV 50000
#define NE 5000
#define NC 16
#define TAU_INV 2.0f
#define EPS 1e-8f

#define NCH 100         // v-chunks (part round-trip 67.6 MB)
#define VCH 500         // NV / NCH
#define GRP 4           // H prefetch ring depth (divides VCH)
#define EPL 2           // edges per lane: acc = 64 VGPR -> 4 blocks/CU
#define NXB 10          // x-blocks; 10 * 256 lanes * 2 edges = 5120 slots >= 5000
#define NBLK (NXB * NCH)   // 1000 = 250 CU * 4 blocks
#define NLANE 5120

typedef float vf4 __attribute__((ext_vector_type(4)));
typedef float vf2 __attribute__((ext_vector_type(2)));

// ---------------- softmax: one thread per row, both pred_s and pred_t.
// Output layout: p[v][32] = [softmax(pred_s[v]) (16) | softmax(pred_t[v]) (16)]
__global__ __launch_bounds__(256) void softmax_kernel(
    const float* __restrict__ pred_s, const float* __restrict__ pred_t,
    float* __restrict__ p) {
  int i = blockIdx.x * 256 + threadIdx.x;
  if (i >= 2 * NV) return;
  const float* src;
  float* dst;
  if (i < NV) { src = pred_s + (size_t)i * NC; dst = p + (size_t)i * 32; }
  else        { int j = i - NV; src = pred_t + (size_t)j * NC; dst = p + (size_t)j * 32 + 16; }
  float4 a = ((const float4*)src)[0];
  float4 b = ((const float4*)src)[1];
  float4 c = ((const float4*)src)[2];
  float4 d = ((const float4*)src)[3];
  float x[16] = {a.x,a.y,a.z,a.w, b.x,b.y,b.z,b.w, c.x,c.y,c.z,c.w, d.x,d.y,d.z,d.w};
  float mx = x[0];
#pragma unroll
  for (int k = 1; k < 16; ++k) mx = fmaxf(mx, x[k]);
  float sum = 0.f;
#pragma unroll
  for (int k = 0; k < 16; ++k) { x[k] = expf(x[k] - mx); sum += x[k]; }
  float inv = 1.f / sum;
#pragma unroll
  for (int k = 0; k < 16; ++k) x[k] *= inv;
  float4 o0 = {x[0], x[1], x[2], x[3]};
  float4 o1 = {x[4], x[5], x[6], x[7]};
  float4 o2 = {x[8], x[9], x[10], x[11]};
  float4 o3 = {x[12], x[13], x[14], x[15]};
  ((float4*)dst)[0] = o0;
  ((float4*)dst)[1] = o1;
  ((float4*)dst)[2] = o2;
  ((float4*)dst)[3] = o3;
}

// 8 FMAs: one p-quad (4 classes) x 2 edges
#define Q4(ACC, B) \
  ACC[B+0].x = fmaf(h.x, q.x, ACC[B+0].x); ACC[B+0].y = fmaf(h.y, q.x, ACC[B+0].y); \
  ACC[B+1].x = fmaf(h.x, q.y, ACC[B+1].x); ACC[B+1].y = fmaf(h.y, q.y, ACC[B+1].y); \
  ACC[B+2].x = fmaf(h.x, q.z, ACC[B+2].x); ACC[B+2].y = fmaf(h.y, q.z, ACC[B+2].y); \
  ACC[B+3].x = fmaf(h.x, q.w, ACC[B+3].x); ACC[B+3].y = fmaf(h.y, q.w, ACC[B+3].y);

// ---------------- main accumulation: NO LDS. p-row fetched per row at a
// wave-uniform address (one L1 line broadcast / scalarized load); H streamed
// directly as f32 vf2 with a GRP-deep register ring.
// part layout: part[y][k][NLANE], k: 0..15 S, 16..31 T, 32 deg
__global__ __launch_bounds__(256, 4) void accum_kernel(
    const float* __restrict__ H, const float* __restrict__ p,
    float* __restrict__ part) {
  int b = blockIdx.x;
  // NBLK=1000 = 8*125: bijective XCD swizzle; consecutive items share y-chunk
  int item = (b & 7) * 125 + (b >> 3);
  int xb = item % NXB;
  int y  = item / NXB;
  int e0 = EPL * (xb * 256 + (int)threadIdx.x);
  if (e0 > NE - EPL) e0 = NE - EPL;   // dup lanes write identical values: benign
  int v0 = y * VCH;

  float2 aS[16], aT[16];
#pragma unroll
  for (int k = 0; k < 16; ++k) {
    aS[k] = make_float2(0.f, 0.f);
    aT[k] = make_float2(0.f, 0.f);
  }
  float2 dg = make_float2(0.f, 0.f);

  const float* __restrict__ hp = H + (size_t)v0 * NE + e0;
  const float4* __restrict__ pr = (const float4*)(p + (size_t)v0 * 32);  // uniform

  vf2 hc[GRP];
#pragma unroll
  for (int u = 0; u < GRP; ++u)
    hc[u] = *(const vf2*)(hp + (size_t)u * NE);

  for (int vb = 0; vb < VCH; vb += GRP) {
    int nb = (vb + GRP < VCH) ? vb + GRP : vb;   // last iter: benign re-load
    vf2 hn[GRP];
#pragma unroll
    for (int u = 0; u < GRP; ++u)
      hn[u] = *(const vf2*)(hp + (size_t)(nb + u) * NE);

#pragma unroll
    for (int u = 0; u < GRP; ++u) {
      const float4* __restrict__ r = pr + (size_t)(vb + u) * 8;  // wave-uniform
      vf2 h = hc[u];
      dg.x += h.x; dg.y += h.y;
      float4 q;
      q = r[0]; Q4(aS, 0)
      q = r[1]; Q4(aS, 4)
      q = r[2]; Q4(aS, 8)
      q = r[3]; Q4(aS, 12)
      q = r[4]; Q4(aT, 0)
      q = r[5]; Q4(aT, 4)
      q = r[6]; Q4(aT, 8)
      q = r[7]; Q4(aT, 12)
    }
#pragma unroll
    for (int u = 0; u < GRP; ++u) hc[u] = hn[u];
  }

  // normal stores: part (67.6 MB) stays mostly L3-resident for reduce_kernel
  float* op = part + (size_t)y * 33 * NLANE + e0;
#pragma unroll
  for (int k = 0; k < 16; ++k) {
    vf2 w = {aS[k].x, aS[k].y};
    *(vf2*)(op + (size_t)k * NLANE) = w;
  }
#pragma unroll
  for (int k = 0; k < 16; ++k) {
    vf2 w = {aT[k].x, aT[k].y};
    *(vf2*)(op + (size_t)(16 + k) * NLANE) = w;
  }
  {
    vf2 w = {dg.x, dg.y};
    *(vf2*)(op + (size_t)32 * NLANE) = w;
  }
}

// ---------------- reduce the NCH partials: acc[k][NLANE] = sum_y part[y][k][NLANE]
__global__ __launch_bounds__(256) void reduce_kernel(
    const float* __restrict__ part, float* __restrict__ acc) {
  int i = blockIdx.x * 256 + threadIdx.x;
  if (i >= 33 * NLANE) return;
  float s = 0.f;
#pragma unroll 4
  for (int y = 0; y < NCH; ++y)
    s += part[(size_t)y * 33 * NLANE + i];
  acc[i] = s;
}

// ---------------- per-edge KL + masked reduction (single block, 256 threads)
// acc layout: acc[k*NLANE + e]; S at k, T at 16+k, deg at 32
__global__ __launch_bounds__(256) void kl_kernel(
    const float* __restrict__ acc, const unsigned char* __restrict__ e_mask,
    float* __restrict__ out) {
  __shared__ float snum[4];
  __shared__ float scnt[4];
  int t = threadIdx.x;
  float num = 0.f, cnt = 0.f;
  for (int e = t; e < NE; e += 256) {
    if (e_mask[e]) {
      float deg = acc[(size_t)32 * NLANE + e];
      float invd = 1.f / deg;
      float kl = 0.f;
#pragma unroll
      for (int k = 0; k < 16; ++k) {
        float ms = acc[(size_t)k * NLANE + e] * invd;
        float mt = acc[(size_t)(16 + k) * NLANE + e] * invd;
        float xs = ms * TAU_INV + EPS;
        float xt = mt * TAU_INV + EPS;
        kl += xt * (logf(xt) - logf(xs));
      }
      num += kl;
      cnt += 1.f;
    }
  }
#pragma unroll
  for (int off = 32; off > 0; off >>= 1) {
    num += __shfl_down(num, off, 64);
    cnt += __shfl_down(cnt, off, 64);
  }
  if ((t & 63) == 0) { snum[t >> 6] = num; scnt[t >> 6] = cnt; }
  __syncthreads();
  if (t == 0) {
    float n = snum[0] + snum[1] + snum[2] + snum[3];
    float c2 = scnt[0] + scnt[1] + scnt[2] + scnt[3];
    out[0] = n / fmaxf(c2, 1.f);
  }
}

extern "C" void kernel_launch(void* const* d_in, const int* in_sizes, int n_in,
                              void* d_out, int out_size, void* d_ws, size_t ws_size,
                              hipStream_t stream) {
  const float* pred_s = (const float*)d_in[0];
  const float* pred_t = (const float*)d_in[1];
  const float* H      = (const float*)d_in[2];
  const unsigned char* e_mask = (const unsigned char*)d_in[3];

  float* ws   = (float*)d_ws;
  float* p    = ws;                                    // NV*32         (6.40 MB)
  float* acc  = ws + (size_t)NV * 32;                  // 33*NLANE      (0.68 MB)
  float* part = acc + (size_t)33 * NLANE;              // NCH*33*NLANE  (67.6 MB)

  softmax_kernel<<<dim3((2 * NV + 255) / 256), 256, 0, stream>>>(pred_s, pred_t, p);
  accum_kernel<<<dim3(NBLK), 256, 0, stream>>>(H, p, part);
  reduce_kernel<<<dim3((33 * NLANE + 255) / 256), 256, 0, stream>>>(part, acc);
  kl_kernel<<<1, 256, 0, stream>>>(acc, e_mask, (float*)d_out);
}